// Round 14
// baseline (6352.239 us; speedup 1.0000x reference)
//
#include <hip/hip_runtime.h>
#include <hip/hip_bf16.h>
#include <stdint.h>

typedef __bf16 bf16_t;
typedef bf16_t bf16x8 __attribute__((ext_vector_type(8)));
typedef float  f32x4  __attribute__((ext_vector_type(4)));
typedef float  f32x16 __attribute__((ext_vector_type(16)));
typedef unsigned int u32x4 __attribute__((ext_vector_type(4)));

#define I_DIM 512
#define H_DIM 1024
#define B_DIM 64
#define S_DIM 512
#define G4    4096   // 4*H
#define CHUNK 16     // steps per xp ring slot
#define NCHUNK (S_DIM / CHUNK)
#define XPSLOT_ELEMS ((size_t)CHUNK * 64 * G4)   // 1024*4096 bf16 = 8 MB

// ---------------- workspace layout (bytes) — total ~34 MB ----------------
#define O_WXT   0x0000000ULL  // [4096][512]  bf16 = 4 MB   (packed WxT, row-major)
#define O_WHTF  0x0400000ULL  // [128][64][64][8] bf16 = 8 MB (Wh in MFMA B-frag order)
#define O_BIAS  0x0C00000ULL  // [4096] f32 = 16 KB
#define O_HBUF  0x0D00000ULL  // 2 slots * 256 KB tagged h: u32 = (bf16<<16)|step_tag
#define O_BAR   0x0D80000ULL  // 32 KB counters: xp_done[] + consumed[]
#define O_XP    0x1200000ULL  // 2 slots * [1024][4096] bf16 = 16 MB

// bar[] u32 indices (64-spaced to avoid false sharing)
#define XPD_IDX(c)  (2048 + (c) * 64)   // xp chunk c published (256 arrivals)
#define CONS_IDX(c) (4096 + (c) * 64)   // xp chunk c consumed  (256 arrivals)

__device__ __forceinline__ float sigm(float x)      { return 1.f / (1.f + __expf(-x)); }
__device__ __forceinline__ float tanh_fast(float x) { return 1.f - 2.f / (__expf(2.f * x) + 1.f); }

// Packed gate-column permutation: packed col p = q*32 + g*8 + jj  <->  hidden j = q*8+jj, gate g (0:i 1:f 2:g 3:o)

__global__ void k_pack_wx(const float* __restrict__ w0, const float* __restrict__ w1,
                          const float* __restrict__ w2, const float* __restrict__ w3,
                          bf16_t* __restrict__ wxt) {
    int tid = blockIdx.x * 256 + threadIdx.x;
    int k = tid >> 12;
    int p = tid & 4095;
    int q = p >> 5, g = (p >> 3) & 3, jj = p & 7;
    int j = q * 8 + jj;
    const float* src = (g == 0) ? w0 : (g == 1) ? w1 : (g == 2) ? w2 : w3;
    wxt[(size_t)p * I_DIM + k] = (bf16_t)src[k * H_DIM + j];
}

// Wh -> global MFMA B-fragment order: whtf[q][ks][lane][8]
//   element = WhT[p = q*32 + (lane&31)][k = ks*16 + (lane>>5)*8 + e]
__global__ void k_pack_whf(const float* __restrict__ w0, const float* __restrict__ w1,
                           const float* __restrict__ w2, const float* __restrict__ w3,
                           bf16_t* __restrict__ whtf) {
    int idx = blockIdx.x * 256 + threadIdx.x;     // 0..4194303
    int e    = idx & 7;
    int lane = (idx >> 3) & 63;
    int ks   = (idx >> 9) & 63;
    int q    = idx >> 15;                          // 0..127
    int k = ks * 16 + (lane >> 5) * 8 + e;
    int c = lane & 31;
    int g = c >> 3, jj = c & 7;
    int j = q * 8 + jj;
    const float* src = (g == 0) ? w0 : (g == 1) ? w1 : (g == 2) ? w2 : w3;
    whtf[idx] = (bf16_t)src[k * H_DIM + j];
}

__global__ void k_pack_bias(const float* bi0, const float* bh0, const float* bi1, const float* bh1,
                            const float* bi2, const float* bh2, const float* bi3, const float* bh3,
                            float* __restrict__ bias) {
    int p = blockIdx.x * 256 + threadIdx.x;
    int q = p >> 5, g = (p >> 3) & 3, jj = p & 7;
    int j = q * 8 + jj;
    const float* a = (g == 0) ? bi0 : (g == 1) ? bi1 : (g == 2) ? bi2 : bi3;
    const float* b = (g == 0) ? bh0 : (g == 1) ? bh1 : (g == 2) ? bh2 : bh3;
    bias[p] = a[j] + b[j];
}

// ---------------- the whole LSTM in ONE persistent dispatch ----------------
// R20: tagged-word dataflow. The barrier's serial chain (drain->grp->root->
// poll->release->h-load, ~4 L3 RTs) is the last unattacked cost. Fuse signal
// into data: h element = u32 (bf16<<16)|step_tag, stored as atomic u64
// AGENT (R8-proven coherent). Consumer retry-loads its quarter's 32 B/lane
// granules until every u64's tag == t — no flags, no drain-before-signal,
// no release barrier; when the check passes the data is in registers.
// Chain = store lands (~450cy) + in-flight retry observes (~900cy) + MFMA.
// Each u64 = one producer atomic store -> tag+data cannot tear.
// WAR (2-slot ring): WG writing h_{t+2} read complete h_{t+1} => every WG
// wrote h_{t+1} => every WG finished reading h_t. Replay: 512 KB memset
// zeroes tags (h0=0 tag 0 = expected at t=0); tags t<=512 << 65536.
// Why this beats R10/R11's flags (8.3-8.6): no last-of-128 detection, no
// post-detection serialized h-load, per-quarter granularity (32 producers).
// Why it won't R14-storm: polls spread over 256 KB (no 8-cacheline hotspot).
// Register care: unpack in 4 blocks of 4 i's (transient 32 VGPR, not 128).
// xproj fusion + xp ring pacing unchanged (R13).
__global__ __launch_bounds__(256, 2) void k_mega(
    const float* __restrict__ x, const bf16_t* __restrict__ wxt,
    const float* __restrict__ bias, const bf16_t* __restrict__ whtf,
    bf16_t* __restrict__ xp, uint32_t* __restrict__ hbuf,
    float* __restrict__ out, uint32_t* __restrict__ bar)
{
    __shared__ float Pl[4][16][64];               // step: partials, 16 KB
    __shared__ __align__(16) bf16_t Hlds[256];    // step: h staging
    __shared__ __align__(16) bf16_t Al[8 * 64 * 8];  // xproj: A tile, 8 KB
    __shared__ __align__(16) bf16_t Bl[8 * 64 * 8];  // xproj: B tile, 8 KB
    const int tid  = threadIdx.x;

    if (blockIdx.x >= 256) {
        // ---------------- xproj producer path ----------------
        const int xbid = blockIdx.x - 256;        // 0..255
        const int n0 = (xbid & 31) * 128;         // col tile
        const int rt = (xbid >> 5) * 128;         // row tile within chunk (0..896)
        const int wv = tid >> 6;
        const int lane = tid & 63;
        const int mq = wv >> 1, nq = wv & 1;
        const int l15 = lane & 15, quad = lane >> 4;

        for (int sc = 0; sc < NCHUNK; ++sc) {
            if (sc >= 2) {
                if (tid == 0) {
                    while (__hip_atomic_load(&bar[CONS_IDX(sc - 2)], __ATOMIC_RELAXED,
                                             __HIP_MEMORY_SCOPE_AGENT) < 256u)
                        __builtin_amdgcn_s_sleep(2);
                }
                __syncthreads();
            }
            bf16_t* xps = xp + (size_t)(sc & 1) * XPSLOT_ELEMS;
            const int r_base = sc * (CHUNK * 64);

            f32x4 acc[4][4] = {};
            for (int kk = 0; kk < I_DIM; kk += 32) {
                __syncthreads();
                #pragma unroll
                for (int sidx = 0; sidx < 2; ++sidx) {
                    int s = tid + sidx * 256;
                    int mt = s >> 6, l = s & 63;
                    int m = l & 15, kb = (l >> 4) * 8;
                    int r = r_base + rt + mt * 16 + m;
                    int b = r & 63, si = r >> 6;
                    const float* gp = x + ((size_t)(b * S_DIM + si)) * I_DIM + kk + kb;
                    float4 v0 = *(const float4*)gp;
                    float4 v1 = *(const float4*)(gp + 4);
                    bf16x8 a;
                    a[0] = (bf16_t)v0.x; a[1] = (bf16_t)v0.y; a[2] = (bf16_t)v0.z; a[3] = (bf16_t)v0.w;
                    a[4] = (bf16_t)v1.x; a[5] = (bf16_t)v1.y; a[6] = (bf16_t)v1.z; a[7] = (bf16_t)v1.w;
                    *(bf16x8*)&Al[s * 8] = a;
                    bf16x8 bv = *(const bf16x8*)(wxt + (size_t)(n0 + mt * 16 + m) * I_DIM + kk + kb);
                    *(bf16x8*)&Bl[s * 8] = bv;
                }
                __syncthreads();
                bf16x8 af[4], bfr[4];
                #pragma unroll
                for (int mt = 0; mt < 4; ++mt) af[mt]  = *(bf16x8*)&Al[((mq * 4 + mt) * 64 + lane) * 8];
                #pragma unroll
                for (int nt = 0; nt < 4; ++nt) bfr[nt] = *(bf16x8*)&Bl[((nq * 4 + nt) * 64 + lane) * 8];
                #pragma unroll
                for (int mt = 0; mt < 4; ++mt)
                    #pragma unroll
                    for (int nt = 0; nt < 4; ++nt)
                        acc[mt][nt] = __builtin_amdgcn_mfma_f32_16x16x32_bf16(af[mt], bfr[nt], acc[mt][nt], 0, 0, 0);
            }
            #pragma unroll
            for (int nt = 0; nt < 4; ++nt) {
                int colg = n0 + nq * 64 + nt * 16 + l15;
                float bv = bias[colg];
                #pragma unroll
                for (int mt = 0; mt < 4; ++mt)
                    #pragma unroll
                    for (int r = 0; r < 4; ++r) {
                        int row = rt + mq * 64 + mt * 16 + quad * 4 + r;  // within chunk
                        bf16_t hb = (bf16_t)(acc[mt][nt][r] + bv);
                        __hip_atomic_store((uint16_t*)(xps + (size_t)row * G4 + colg),
                                           __builtin_bit_cast(unsigned short, hb),
                                           __ATOMIC_RELAXED, __HIP_MEMORY_SCOPE_AGENT);
                    }
            }
            asm volatile("s_waitcnt vmcnt(0)" ::: "memory");  // all lanes drained
            __syncthreads();                                   // all waves drained
            if (tid == 0)
                __hip_atomic_fetch_add(&bar[XPD_IDX(sc)], 1u,
                                       __ATOMIC_RELAXED, __HIP_MEMORY_SCOPE_AGENT);
        }
        return;
    }

    // ---------------- step path ----------------
    const int w    = tid >> 6;                    // K-quarter index
    const int lane = tid & 63;
    const int bid  = blockIdx.x;
    const int q    = bid & 127;                   // packed col-block (32 cols)
    const int bh   = bid >> 7;                    // batch half

    const int col  = lane & 31;
    const int ksel = lane >> 5;
    const int gt   = (lane >> 3) & 3;  // 0:i 1:f 2:g 3:o
    const int jj   = lane & 7;

    int rrow[4];
    #pragma unroll
    for (int e = 0; e < 4; ++e) rrow[e] = e + 8 * w + 4 * ksel;

    // Loop-invariant B fragments: loaded ONCE for all 512 steps.
    const bf16_t* bb = whtf + ((size_t)q << 15) + (w << 13) + (lane << 3);
    bf16x8 bfr[16];
    #pragma unroll
    for (int i = 0; i < 16; ++i) bfr[i] = *(const bf16x8*)(bb + i * 512);

    // c-state in registers for the ENTIRE sequence (i-gate lanes only).
    float cst[4] = {0.f, 0.f, 0.f, 0.f};

    // Tagged-h u64 bases (slot = 32768 u64 = 256 KB):
    //   consumer (this wave's quarter): (bh<<14)+(w<<12)+(lane<<2), +i*256
    //   producer (this WG's slice):     ((bh<<13)+(q<<6)+lane)*2
    const int cbase = (bh << 14) + (w << 12) + (lane << 2);
    const int pbase = ((bh << 13) + (q << 6) + lane) << 1;

    for (int c = 0; c < NCHUNK; ++c) {
        // Wait for xp chunk c to be fully published (coarse, 1x per 16 steps).
        if (tid == 0) {
            while (__hip_atomic_load(&bar[XPD_IDX(c)], __ATOMIC_RELAXED,
                                     __HIP_MEMORY_SCOPE_AGENT) < 256u)
                __builtin_amdgcn_s_sleep(2);
        }
        __syncthreads();
        const uint16_t* xpc = (const uint16_t*)(xp + (size_t)(c & 1) * XPSLOT_ELEMS);

        for (int tl = 0; tl < CHUNK; ++tl) {
            const int t = c * CHUNK + tl;
            const uint32_t tag = (uint32_t)t & 0xffffu;

            // xpr first: chunk-static, flies during the tag-gated retry.
            bf16_t xpr[4];
            #pragma unroll
            for (int e = 0; e < 4; ++e) {
                unsigned short v = __hip_atomic_load(
                    &xpc[(size_t)(tl * 64 + bh * 32 + rrow[e]) * G4 + q * 32 + col],
                    __ATOMIC_RELAXED, __HIP_MEMORY_SCOPE_AGENT);
                xpr[e] = __builtin_bit_cast(bf16_t, v);
            }

            // Tag-gated h acquisition: data IS the signal. 64 u64/wave-lane
            // group, unpacked in 4 blocks of 4 i's to bound register pressure.
            const uint64_t* hsrc = (const uint64_t*)hbuf + ((t & 1) << 15) + cbase;
            u32x4 af[16];
            for (;;) {
                int ok = 1;
                #pragma unroll
                for (int ib = 0; ib < 4; ++ib) {
                    uint64_t d[16];
                    #pragma unroll
                    for (int ii = 0; ii < 4; ++ii) {
                        const uint64_t* p = hsrc + (ib * 4 + ii) * 256;
                        d[ii * 4 + 0] = __hip_atomic_load(p + 0, __ATOMIC_RELAXED, __HIP_MEMORY_SCOPE_AGENT);
                        d[ii * 4 + 1] = __hip_atomic_load(p + 1, __ATOMIC_RELAXED, __HIP_MEMORY_SCOPE_AGENT);
                        d[ii * 4 + 2] = __hip_atomic_load(p + 2, __ATOMIC_RELAXED, __HIP_MEMORY_SCOPE_AGENT);
                        d[ii * 4 + 3] = __hip_atomic_load(p + 3, __ATOMIC_RELAXED, __HIP_MEMORY_SCOPE_AGENT);
                    }
                    #pragma unroll
                    for (int ii = 0; ii < 4; ++ii) {
                        u32x4 v;
                        #pragma unroll
                        for (int k2 = 0; k2 < 4; ++k2) {
                            uint64_t dk = d[ii * 4 + k2];
                            uint32_t lo = (uint32_t)dk, hi = (uint32_t)(dk >> 32);
                            v[k2] = (lo >> 16) | (hi & 0xffff0000u);
                            ok &= (int)((lo & 0xffffu) == tag);
                        }
                        af[ib * 4 + ii] = v;
                    }
                }
                if (__all(ok)) break;
            }

            f32x16 acc0 = {}, acc1 = {}, acc2 = {}, acc3 = {};
            #pragma unroll
            for (int i = 0; i < 16; i += 4) {
                acc0 = __builtin_amdgcn_mfma_f32_32x32x16_bf16(__builtin_bit_cast(bf16x8, af[i + 0]), bfr[i + 0], acc0, 0, 0, 0);
                acc1 = __builtin_amdgcn_mfma_f32_32x32x16_bf16(__builtin_bit_cast(bf16x8, af[i + 1]), bfr[i + 1], acc1, 0, 0, 0);
                acc2 = __builtin_amdgcn_mfma_f32_32x32x16_bf16(__builtin_bit_cast(bf16x8, af[i + 2]), bfr[i + 2], acc2, 0, 0, 0);
                acc3 = __builtin_amdgcn_mfma_f32_32x32x16_bf16(__builtin_bit_cast(bf16x8, af[i + 3]), bfr[i + 3], acc3, 0, 0, 0);
            }
            f32x16 accs = acc0 + acc1 + acc2 + acc3;

            #pragma unroll
            for (int e = 0; e < 16; ++e) Pl[w][e][lane] = accs[e];
            __syncthreads();

            #pragma unroll
            for (int e = 0; e < 4; ++e) {
                int eg = w * 4 + e;
                float pre = Pl[0][eg][lane] + Pl[1][eg][lane] + Pl[2][eg][lane] + Pl[3][eg][lane];
                pre += (float)xpr[e];
                float a = (gt == 2) ? tanh_fast(pre) : sigm(pre);

                float fv = __shfl_xor(a, 8, 64);
                float gv = __shfl_xor(a, 16, 64);
                float ov = __shfl_xor(a, 24, 64);
                if (gt == 0) {
                    float cn = fv * cst[e] + a * gv;
                    float hv = ov * tanh_fast(cn);
                    cst[e] = cn;
                    Hlds[rrow[e] * 8 + jj] = (bf16_t)hv;
                    if (t == S_DIM - 1) {
                        int rowg = bh * 32 + rrow[e];
                        int j = q * 8 + jj;
                        out[rowg * H_DIM + j] = hv;            // h_T
                        out[65536 + rowg * H_DIM + j] = cn;    // c_T
                    }
                }
            }
            __syncthreads();   // Hlds complete; also fences Pl reuse next step

            // Publish tagged h slice (wave 0): 2 atomic u64 per lane, tag
            // embedded per u32 — no drain, no flag, no release barrier.
            if (w == 0) {
                const uint32_t ntag = (uint32_t)(t + 1) & 0xffffu;
                uint32_t b01 = *(const uint32_t*)&Hlds[lane * 4];
                uint32_t b23 = *(const uint32_t*)&Hlds[lane * 4 + 2];
                uint64_t d0 = ((uint64_t)((b01 & 0xffff0000u) | ntag) << 32)
                            | ((b01 << 16) | ntag);
                uint64_t d1 = ((uint64_t)((b23 & 0xffff0000u) | ntag) << 32)
                            | ((b23 << 16) | ntag);
                uint64_t* hdst = (uint64_t*)hbuf + (((t + 1) & 1) << 15) + pbase;
                __hip_atomic_store(hdst,     d0, __ATOMIC_RELAXED, __HIP_MEMORY_SCOPE_AGENT);
                __hip_atomic_store(hdst + 1, d1, __ATOMIC_RELAXED, __HIP_MEMORY_SCOPE_AGENT);
            }
        }

        // Chunk consumed: xproj may overwrite this xp slot (for chunk c+2).
        // (The last epilogue __syncthreads joined all waves' xpr reads.)
        if (tid == 0)
            __hip_atomic_fetch_add(&bar[CONS_IDX(c)], 1u,
                                   __ATOMIC_RELAXED, __HIP_MEMORY_SCOPE_AGENT);
    }
}

extern "C" void kernel_launch(void* const* d_in, const int* in_sizes, int n_in,
                              void* d_out, int out_size, void* d_ws, size_t ws_size,
                              hipStream_t stream) {
    const float* x   = (const float*)d_in[0];
    const float* wii = (const float*)d_in[1];
    const float* bii = (const float*)d_in[2];
    const float* whi = (const float*)d_in[3];
    const float* bhi = (const float*)d_in[4];
    const float* wif = (const float*)d_in[5];
    const float* bif = (const float*)d_in[6];
    const float* whf = (const float*)d_in[7];
    const float* bhf = (const float*)d_in[8];
    const float* wig = (const float*)d_in[9];
    const float* big = (const float*)d_in[10];
    const float* whg = (const float*)d_in[11];
    const float* bhg = (const float*)d_in[12];
    const float* wio = (const float*)d_in[13];
    const float* bio = (const float*)d_in[14];
    const float* who = (const float*)d_in[15];
    const float* bho = (const float*)d_in[16];

    char* ws = (char*)d_ws;
    bf16_t*   wxt  = (bf16_t*)(ws + O_WXT);
    bf16_t*   whtf = (bf16_t*)(ws + O_WHTF);
    float*    bias = (float*)(ws + O_BIAS);
    uint32_t* hbuf = (uint32_t*)(ws + O_HBUF);
    uint32_t* bar  = (uint32_t*)(ws + O_BAR);
    bf16_t*   xp   = (bf16_t*)(ws + O_XP);

    hipMemsetAsync(hbuf, 0, 512 * 1024, stream);   // both tagged slots: h0=0, tag 0
    hipMemsetAsync(bar,  0, 32 * 1024, stream);    // all counters (reset each replay)

    k_pack_wx<<<8192, 256, 0, stream>>>(wii, wif, wig, wio, wxt);
    k_pack_whf<<<16384, 256, 0, stream>>>(whi, whf, whg, who, whtf);
    k_pack_bias<<<16, 256, 0, stream>>>(bii, bhi, bif, bhf, big, bhg, bio, bho, bias);

    float* out = (float*)d_out;
    void* args[] = { (void*)&x, (void*)&wxt, (void*)&bias, (void*)&whtf,
                     (void*)&xp, (void*)&hbuf, (void*)&out, (void*)&bar };
    hipError_t err = hipLaunchCooperativeKernel((const void*)k_mega, dim3(512), dim3(256),
                                                args, 0, stream);
    if (err != hipSuccess) {
        // Plain-launch fallback: capacity (2 blocks/CU x 256 CU) == grid, so
        // all 512 blocks are co-resident regardless of dispatch order.
        k_mega<<<512, 256, 0, stream>>>(x, wxt, bias, whtf, xp, hbuf, out, bar);
    }
}